// Round 3
// baseline (628.071 us; speedup 1.0000x reference)
//
#include <hip/hip_runtime.h>

// ProbAttention on MI355X (gfx950). Inputs/outputs fp32; compute in bf16 MFMA
// (mfma_f32_16x16x32_bf16, fp32 accumulate). B=8, L=4096, D=512, H=8, DK=64,
// S=512, CONV_K=3, POOL=2.
//
// Pipeline:
//  0. cvt: x (fp32) -> xb (bf16)                 [B*L*512]
//  1. weight transposes fp32 -> bf16 Bt[N][K]    (Wq/Wk/Wv/comb 512x512, conv 1536x512)
//  2. gather xb rows: xkg (K path, double-gather collapsed), xvg (V path)
//  3. Kg = xkg @ Wk, Vg = xvg @ Wv  (bf16 GEMM)
//  4. Vt[b][e][s] = Vg[b][s][e]
//  5. fused attn (Q proj fused) -> Pad[b][l+1][e]  (rows 0, L+1 zeroed = SAME pad)
//  6. conv-as-GEMM K=1536 + bias + ELU + MaxPool2 -> Pool [B][2048][512] bf16
//  7. final GEMM + bias -> out (fp32)
//
// Workspace (79.2 MB):
//   xb    @ 0          33,554,432   (Pool [16,777,216 B] aliases @0 after attn)
//   Pad   @ 33,554,432 33,570,816   (xkg/xvg/Vg alias its head, dead pre-attn)
//   Kg    @ 67,125,248  4,194,304
//   Vt    @ 71,319,552  4,194,304
//   WqT   @ 75,513,856    524,288
//   WkT   @ 76,038,144    524,288
//   WvT   @ 76,562,432    524,288
//   CombT @ 77,086,720    524,288
//   ConvT @ 77,611,008  1,572,864   -> end 79,183,872

typedef __attribute__((ext_vector_type(8))) short  short8;
typedef __attribute__((ext_vector_type(4))) float  f32x4;

#define LSEQ   4096
#define SK     512
#define EDIM   512
#define LPAD   4098            // L + 2
#define PADROW 2098176         // LPAD * 512 (shorts)

static __device__ __forceinline__ float bf2f(unsigned short h) {
    union { unsigned int u; float f; } v; v.u = ((unsigned int)h) << 16; return v.f;
}
static __device__ __forceinline__ unsigned short f2bf(float f) {
    union { float f; unsigned int u; } v; v.f = f;
    unsigned int r = (v.u + 0x7fffu + ((v.u >> 16) & 1u)) >> 16;
    return (unsigned short)r;
}

// ---------------------------------------------------------------- fp32 -> bf16
__global__ __launch_bounds__(256)
void cvt_bf16(const float* __restrict__ src, unsigned short* __restrict__ dst)
{
    const size_t i = ((size_t)blockIdx.x * 256 + threadIdx.x) * 8;
    const float4 a = *(const float4*)(src + i);
    const float4 b = *(const float4*)(src + i + 4);
    short8 o;
    o[0] = (short)f2bf(a.x); o[1] = (short)f2bf(a.y);
    o[2] = (short)f2bf(a.z); o[3] = (short)f2bf(a.w);
    o[4] = (short)f2bf(b.x); o[5] = (short)f2bf(b.y);
    o[6] = (short)f2bf(b.z); o[7] = (short)f2bf(b.w);
    *(short8*)(dst + i) = o;
}

// ---------------------------------------------------------------- transpose fp32 -> bf16
// dst[C][R] (bf16) = src[R][C] (fp32), 64x64 tiles.
__global__ __launch_bounds__(256)
void tr_f32_bf16(unsigned short* __restrict__ dst, const float* __restrict__ src,
                 int R, int C)
{
    __shared__ unsigned short T[64][72];
    const int t  = threadIdx.x;
    const int r0 = blockIdx.y * 64, c0 = blockIdx.x * 64;
    const int row = t >> 2, cg = (t & 3) * 16;
    const float* s = src + (size_t)(r0 + row) * C + c0 + cg;
    const float4 f0 = *(const float4*)s;
    const float4 f1 = *(const float4*)(s + 4);
    const float4 f2 = *(const float4*)(s + 8);
    const float4 f3 = *(const float4*)(s + 12);
    T[row][cg + 0]  = f2bf(f0.x); T[row][cg + 1]  = f2bf(f0.y);
    T[row][cg + 2]  = f2bf(f0.z); T[row][cg + 3]  = f2bf(f0.w);
    T[row][cg + 4]  = f2bf(f1.x); T[row][cg + 5]  = f2bf(f1.y);
    T[row][cg + 6]  = f2bf(f1.z); T[row][cg + 7]  = f2bf(f1.w);
    T[row][cg + 8]  = f2bf(f2.x); T[row][cg + 9]  = f2bf(f2.y);
    T[row][cg + 10] = f2bf(f2.z); T[row][cg + 11] = f2bf(f2.w);
    T[row][cg + 12] = f2bf(f3.x); T[row][cg + 13] = f2bf(f3.y);
    T[row][cg + 14] = f2bf(f3.z); T[row][cg + 15] = f2bf(f3.w);
    __syncthreads();
    unsigned short* d = dst + (size_t)(c0 + row) * R + r0 + cg;
    short8 o0, o1;
    #pragma unroll
    for (int k = 0; k < 8; ++k) o0[k] = (short)T[cg + k][row];
    #pragma unroll
    for (int k = 0; k < 8; ++k) o1[k] = (short)T[cg + 8 + k][row];
    *(short8*)d       = o0;
    *(short8*)(d + 8) = o1;
}

// ---------------------------------------------------------------- transpose bf16 -> bf16
// dst[C][R] = src[R][C], 64x64 tiles, batched via blockIdx.z.
__global__ __launch_bounds__(256)
void tr_bf16(unsigned short* __restrict__ dst, const unsigned short* __restrict__ src,
             int R, int C)
{
    __shared__ unsigned short T[64][72];
    const size_t bofs = (size_t)blockIdx.z * (size_t)R * (size_t)C;
    src += bofs; dst += bofs;
    const int t  = threadIdx.x;
    const int r0 = blockIdx.y * 64, c0 = blockIdx.x * 64;
    const int row = t >> 2, cg = (t & 3) * 16;
    const unsigned short* s = src + (size_t)(r0 + row) * C + c0 + cg;
    *(short8*)&T[row][cg]     = *(const short8*)s;
    *(short8*)&T[row][cg + 8] = *(const short8*)(s + 8);
    __syncthreads();
    unsigned short* d = dst + (size_t)(c0 + row) * R + r0 + cg;
    short8 o0, o1;
    #pragma unroll
    for (int k = 0; k < 8; ++k) o0[k] = (short)T[cg + k][row];
    #pragma unroll
    for (int k = 0; k < 8; ++k) o1[k] = (short)T[cg + 8 + k][row];
    *(short8*)d       = o0;
    *(short8*)(d + 8) = o1;
}

// ---------------------------------------------------------------- gather rows (bf16)
// xkg[b][j][:] = xb[b][ sidx[clip(sidx[j],0,511)] ][:]   (double-gather collapsed)
// xvg[b][j][:] = xb[b][ sidx[j] ][:]
__global__ __launch_bounds__(256)
void gather_rows(const unsigned short* __restrict__ xb, const int* __restrict__ sidx,
                 unsigned short* __restrict__ xkg, unsigned short* __restrict__ xvg)
{
    const int blk = blockIdx.x;
    const int b = blk >> 9, j = blk & 511;
    const int t = threadIdx.x;
    int qv = sidx[j];               qv = qv < 0 ? 0 : (qv > LSEQ - 1 ? LSEQ - 1 : qv);
    int cv = qv < SK - 1 ? qv : SK - 1;
    int pv = sidx[cv];              pv = pv < 0 ? 0 : (pv > LSEQ - 1 ? LSEQ - 1 : pv);
    const unsigned int* xs = (const unsigned int*)xb;
    unsigned int* kd = (unsigned int*)xkg;
    unsigned int* vd = (unsigned int*)xvg;
    const size_t dst = ((size_t)b * SK + j) * 256 + t;
    kd[dst] = xs[((size_t)b * LSEQ + pv) * 256 + t];
    vd[dst] = xs[((size_t)b * LSEQ + qv) * 256 + t];
}

// ---------------------------------------------------------------- zero pad rows
__global__ __launch_bounds__(256)
void zero_pad(unsigned short* __restrict__ attpad)
{
    const int i = blockIdx.x * 256 + threadIdx.x;   // 0..4095
    const int b = i >> 9, c = i & 511;
    attpad[(size_t)b * PADROW + c] = 0;
    attpad[(size_t)b * PADROW + (size_t)(LPAD - 1) * 512 + c] = 0;
}

// ---------------------------------------------------------------- GEMM 128x128x32
// C = A[M][K] @ Bt[512][K]^T (bf16 in, fp32 acc). N fixed 512.
// MODE 0: bf16 store, no bias.
// MODE 1: A rows from att_pad (conv window), +bias(fp32), ELU, MaxPool2 -> bf16 Pool.
// MODE 2: +bias(fp32), fp32 store (final output).
template<int MODE>
__global__ __launch_bounds__(256)
void gemm128(const unsigned short* __restrict__ A, const unsigned short* __restrict__ Bt,
             const float* __restrict__ bias, void* __restrict__ Cout, int K)
{
    __shared__ unsigned short As[128 * 40];
    __shared__ unsigned short Bs[128 * 40];
    const int t    = threadIdx.x;
    const int n0   = blockIdx.x * 128;
    const int m0   = blockIdx.y * 128;
    const int srow = t >> 1, scg = (t & 1) * 16;
    const int lane = t & 63, wv = t >> 6;
    const int q = lane >> 4, ln = lane & 15;
    const int wm = (wv & 1) * 64, wn = (wv >> 1) * 64;

    const unsigned short* abase;
    if (MODE == 1) {
        const int gr = m0 + srow;
        abase = A + (size_t)(gr >> 12) * PADROW + (size_t)(gr & 4095) * 512;
    } else {
        abase = A + (size_t)(m0 + srow) * K;
    }
    const unsigned short* bbase = Bt + (size_t)(n0 + srow) * K;

    const f32x4 zero = {0.f, 0.f, 0.f, 0.f};
    f32x4 acc[4][4];
    #pragma unroll
    for (int i = 0; i < 4; ++i)
        #pragma unroll
        for (int j = 0; j < 4; ++j) acc[i][j] = zero;

    short8 av0 = *(const short8*)(abase + scg);
    short8 av1 = *(const short8*)(abase + scg + 8);
    short8 bv0 = *(const short8*)(bbase + scg);
    short8 bv1 = *(const short8*)(bbase + scg + 8);

    for (int k0 = 0; k0 < K; k0 += 32) {
        __syncthreads();
        *(short8*)&As[srow * 40 + scg]     = av0;
        *(short8*)&As[srow * 40 + scg + 8] = av1;
        *(short8*)&Bs[srow * 40 + scg]     = bv0;
        *(short8*)&Bs[srow * 40 + scg + 8] = bv1;
        __syncthreads();
        if (k0 + 32 < K) {   // prefetch next tile while MFMAs run
            av0 = *(const short8*)(abase + k0 + 32 + scg);
            av1 = *(const short8*)(abase + k0 + 32 + scg + 8);
            bv0 = *(const short8*)(bbase + k0 + 32 + scg);
            bv1 = *(const short8*)(bbase + k0 + 32 + scg + 8);
        }
        short8 af[4], bf[4];
        #pragma unroll
        for (int mt = 0; mt < 4; ++mt)
            af[mt] = *(const short8*)&As[(wm + mt * 16 + ln) * 40 + q * 8];
        #pragma unroll
        for (int nt = 0; nt < 4; ++nt)
            bf[nt] = *(const short8*)&Bs[(wn + nt * 16 + ln) * 40 + q * 8];
        #pragma unroll
        for (int mt = 0; mt < 4; ++mt)
            #pragma unroll
            for (int nt = 0; nt < 4; ++nt)
                acc[mt][nt] = __builtin_amdgcn_mfma_f32_16x16x32_bf16(af[mt], bf[nt], acc[mt][nt], 0, 0, 0);
    }

    if (MODE == 0) {
        unsigned short* C = (unsigned short*)Cout;
        #pragma unroll
        for (int mt = 0; mt < 4; ++mt)
            #pragma unroll
            for (int r = 0; r < 4; ++r) {
                const int grow = m0 + wm + mt * 16 + q * 4 + r;
                unsigned short* cp = C + (size_t)grow * 512 + n0 + wn + ln;
                #pragma unroll
                for (int nt = 0; nt < 4; ++nt) cp[nt * 16] = f2bf(acc[mt][nt][r]);
            }
    } else if (MODE == 2) {
        float* C = (float*)Cout;
        float bb[4];
        #pragma unroll
        for (int nt = 0; nt < 4; ++nt) bb[nt] = bias[n0 + wn + nt * 16 + ln];
        #pragma unroll
        for (int mt = 0; mt < 4; ++mt)
            #pragma unroll
            for (int r = 0; r < 4; ++r) {
                const int grow = m0 + wm + mt * 16 + q * 4 + r;
                float* cp = C + (size_t)grow * 512 + n0 + wn + ln;
                #pragma unroll
                for (int nt = 0; nt < 4; ++nt) cp[nt * 16] = acc[mt][nt][r] + bb[nt];
            }
    } else { // MODE 1: conv epilogue, bias + ELU + maxpool(2) over row pairs
        unsigned short* C = (unsigned short*)Cout;
        float bb[4];
        #pragma unroll
        for (int nt = 0; nt < 4; ++nt) bb[nt] = bias[n0 + wn + nt * 16 + ln];
        #pragma unroll
        for (int mt = 0; mt < 4; ++mt) {
            const int grow = m0 + wm + mt * 16 + q * 4;     // multiple of 4
            const int b = grow >> 12, l = grow & 4095;      // l even
            unsigned short* cp = C + ((size_t)b * 2048 + (l >> 1)) * 512 + n0 + wn + ln;
            #pragma unroll
            for (int nt = 0; nt < 4; ++nt) {
                float v0 = acc[mt][nt][0] + bb[nt]; v0 = v0 > 0.f ? v0 : __expf(v0) - 1.f;
                float v1 = acc[mt][nt][1] + bb[nt]; v1 = v1 > 0.f ? v1 : __expf(v1) - 1.f;
                float v2 = acc[mt][nt][2] + bb[nt]; v2 = v2 > 0.f ? v2 : __expf(v2) - 1.f;
                float v3 = acc[mt][nt][3] + bb[nt]; v3 = v3 > 0.f ? v3 : __expf(v3) - 1.f;
                cp[nt * 16]       = f2bf(fmaxf(v0, v1));
                cp[512 + nt * 16] = f2bf(fmaxf(v2, v3));
            }
        }
    }
}

// ---------------------------------------------------------------- fused attention
// grid (L/64, H, B), 256 threads = 4 waves; wave w owns q-rows w*16..w*16+15.
// Phase 0: Q = xb @ WqT[h cols] (fused; LDS round-trip C-layout -> A-layout).
// Phase 1: scores -> LDS bf16, flat softmax over S=512.
// Phase 2: P@V -> att_pad[b][l+1][h*64+d].
__global__ __launch_bounds__(256)
void attn_fused(const unsigned short* __restrict__ xb, const unsigned short* __restrict__ WqT,
                const unsigned short* __restrict__ Kg, const unsigned short* __restrict__ Vt,
                unsigned short* __restrict__ attpad)
{
    __shared__ unsigned short Ps[64][520];
    __shared__ unsigned short Qs[64][72];
    __shared__ float s_inv[64];
    const int t = threadIdx.x;
    const int wv = t >> 6, lane = t & 63, q = lane >> 4, ln = lane & 15;
    const int l0 = blockIdx.x * 64, h = blockIdx.y, b = blockIdx.z;
    const f32x4 zero = {0.f, 0.f, 0.f, 0.f};

    // --- phase 0: Q projection (m=16 rows of this wave, n=64 head cols, k=512)
    f32x4 qacc[4];
    #pragma unroll
    for (int i = 0; i < 4; ++i) qacc[i] = zero;
    const unsigned short* xr = xb + ((size_t)(b * LSEQ + l0 + wv * 16 + ln)) * 512 + q * 8;
    const unsigned short* wq = WqT + ((size_t)(h * 64 + ln)) * 512 + q * 8;
    for (int ks = 0; ks < 16; ++ks) {
        const short8 ax = *(const short8*)(xr + ks * 32);
        #pragma unroll
        for (int nt = 0; nt < 4; ++nt) {
            const short8 bw = *(const short8*)(wq + nt * 16 * 512 + ks * 32);
            qacc[nt] = __builtin_amdgcn_mfma_f32_16x16x32_bf16(ax, bw, qacc[nt], 0, 0, 0);
        }
    }
    #pragma unroll
    for (int nt = 0; nt < 4; ++nt)
        #pragma unroll
        for (int r = 0; r < 4; ++r)
            Qs[wv * 16 + q * 4 + r][nt * 16 + ln] = f2bf(qacc[nt][r]);
    __syncthreads();
    const short8 aq0 = *(const short8*)&Qs[wv * 16 + ln][q * 8];
    const short8 aq1 = *(const short8*)&Qs[wv * 16 + ln][q * 8 + 32];

    // --- phase 1: scores D[m=l][n=j] = Q . K^T, scale 1/8, bf16 to LDS
    for (int nt = 0; nt < 32; ++nt) {
        const unsigned short* kb = Kg + ((size_t)(b * SK + nt * 16 + ln)) * 512 + h * 64 + q * 8;
        const short8 bk0 = *(const short8*)kb;
        const short8 bk1 = *(const short8*)(kb + 32);
        f32x4 acc = zero;
        acc = __builtin_amdgcn_mfma_f32_16x16x32_bf16(aq0, bk0, acc, 0, 0, 0);
        acc = __builtin_amdgcn_mfma_f32_16x16x32_bf16(aq1, bk1, acc, 0, 0, 0);
        #pragma unroll
        for (int r = 0; r < 4; ++r)
            Ps[wv * 16 + q * 4 + r][nt * 16 + ln] = f2bf(acc[r] * 0.125f);
    }
    __syncthreads();

    // --- softmax: 4 threads per row, 128 cols each
    {
        const int row = t >> 2, part = t & 3, cb = part * 128;
        float mx = -1e30f;
        for (int c8 = 0; c8 < 16; ++c8) {
            const short8 v = *(const short8*)&Ps[row][cb + c8 * 8];
            #pragma unroll
            for (int k = 0; k < 8; ++k) mx = fmaxf(mx, bf2f((unsigned short)v[k]));
        }
        mx = fmaxf(mx, __shfl_xor(mx, 1));
        mx = fmaxf(mx, __shfl_xor(mx, 2));
        float sum = 0.f;
        for (int c8 = 0; c8 < 16; ++c8) {
            const short8 v = *(const short8*)&Ps[row][cb + c8 * 8];
            short8 o;
            #pragma unroll
            for (int k = 0; k < 8; ++k) {
                const float p = __expf(bf2f((unsigned short)v[k]) - mx);
                sum += p;
                o[k] = (short)f2bf(p);
            }
            *(short8*)&Ps[row][cb + c8 * 8] = o;
        }
        sum += __shfl_xor(sum, 1);
        sum += __shfl_xor(sum, 2);
        if (part == 0) s_inv[row] = 1.f / sum;
    }
    __syncthreads();

    // --- phase 2: O = P @ V : m = 16 q-rows (this wave), n = 64 d, k = 512
    f32x4 o[4];
    #pragma unroll
    for (int i = 0; i < 4; ++i) o[i] = zero;
    for (int ks = 0; ks < 16; ++ks) {
        const short8 ap = *(const short8*)&Ps[wv * 16 + ln][ks * 32 + q * 8];
        #pragma unroll
        for (int nt = 0; nt < 4; ++nt) {
            const short8 bv = *(const short8*)(Vt + ((size_t)(b * EDIM + h * 64 + nt * 16 + ln)) * SK + ks * 32 + q * 8);
            o[nt] = __builtin_amdgcn_mfma_f32_16x16x32_bf16(ap, bv, o[nt], 0, 0, 0);
        }
    }
    #pragma unroll
    for (int nt = 0; nt < 4; ++nt)
        #pragma unroll
        for (int r = 0; r < 4; ++r) {
            const int rl = wv * 16 + q * 4 + r;
            const float val = o[nt][r] * s_inv[rl];
            attpad[((size_t)b * PADROW) + (size_t)(l0 + rl + 1) * 512 + h * 64 + nt * 16 + ln] = f2bf(val);
        }
}

// ---------------------------------------------------------------- launcher
extern "C" void kernel_launch(void* const* d_in, const int* in_sizes, int n_in,
                              void* d_out, int out_size, void* d_ws, size_t ws_size,
                              hipStream_t stream)
{
    const float* x    = (const float*)d_in[0];
    const float* Wq   = (const float*)d_in[1];
    const float* Wk   = (const float*)d_in[2];
    const float* Wv   = (const float*)d_in[3];
    const float* cw   = (const float*)d_in[4];   // [1536][512] flat fp32
    const float* cb   = (const float*)d_in[5];
    const float* mw   = (const float*)d_in[6];
    const float* mb   = (const float*)d_in[7];
    const int*   sidx = (const int*)d_in[8];
    float* out = (float*)d_out;

    char* ws = (char*)d_ws;
    unsigned short* xb    = (unsigned short*)(ws + 0);           // 33,554,432 B
    unsigned short* Pool  = (unsigned short*)(ws + 0);           // alias (xb dead post-attn)
    unsigned short* Pad   = (unsigned short*)(ws + 33554432);    // 33,570,816 B
    unsigned short* xkg   = (unsigned short*)(ws + 33554432);    // alias Pad head
    unsigned short* xvg   = (unsigned short*)(ws + 37748736);    // alias
    unsigned short* Vg    = (unsigned short*)(ws + 41943040);    // alias
    unsigned short* Kg    = (unsigned short*)(ws + 67125248);    //  4,194,304 B
    unsigned short* Vt    = (unsigned short*)(ws + 71319552);    //  4,194,304 B
    unsigned short* WqT   = (unsigned short*)(ws + 75513856);    //    524,288 B
    unsigned short* WkT   = (unsigned short*)(ws + 76038144);
    unsigned short* WvT   = (unsigned short*)(ws + 76562432);
    unsigned short* CombT = (unsigned short*)(ws + 77086720);
    unsigned short* ConvT = (unsigned short*)(ws + 77611008);    // 1,572,864 B -> end 79,183,872

    dim3 blk(256);

    // 0. x -> bf16
    cvt_bf16<<<dim3(8192), blk, 0, stream>>>(x, xb);

    // 1. weight transposes (fp32 -> bf16): dst[N][K] = W[K][N]
    tr_f32_bf16<<<dim3(8, 8),  blk, 0, stream>>>(WqT,   Wq, 512, 512);
    tr_f32_bf16<<<dim3(8, 8),  blk, 0, stream>>>(WkT,   Wk, 512, 512);
    tr_f32_bf16<<<dim3(8, 8),  blk, 0, stream>>>(WvT,   Wv, 512, 512);
    tr_f32_bf16<<<dim3(8, 8),  blk, 0, stream>>>(CombT, mw, 512, 512);
    tr_f32_bf16<<<dim3(8, 24), blk, 0, stream>>>(ConvT, cw, 1536, 512);

    // 2. gathers (xkg/xvg in Pad head; consumed before zero_pad/attn)
    gather_rows<<<dim3(4096), blk, 0, stream>>>(xb, sidx, xkg, xvg);

    // 3. K/V projections (per-batch 512 gathered rows)
    gemm128<0><<<dim3(4, 32), blk, 0, stream>>>(xkg, WkT, nullptr, Kg, 512);
    gemm128<0><<<dim3(4, 32), blk, 0, stream>>>(xvg, WvT, nullptr, Vg, 512);

    // 4. Vt[b][e][s] = Vg[b][s][e]
    tr_bf16<<<dim3(8, 8, 8), blk, 0, stream>>>(Vt, Vg, 512, 512);

    // 5. attention (Q projection fused; writes Pad rows 1..L)
    zero_pad<<<dim3(16), blk, 0, stream>>>(Pad);
    attn_fused<<<dim3(64, 8, 8), blk, 0, stream>>>(xb, WqT, Kg, Vt, Pad);

    // 6. conv (K=1536) + bias + ELU + pool -> Pool (aliases dead xb)
    gemm128<1><<<dim3(4, 256), blk, 0, stream>>>(Pad, ConvT, cb, Pool, 1536);

    // 7. final dense + bias -> out (fp32)
    gemm128<2><<<dim3(4, 128), blk, 0, stream>>>(Pool, CombT, mb, out, 512);
}

// Round 4
// 534.705 us; speedup vs baseline: 1.1746x; 1.1746x over previous
//
#include <hip/hip_runtime.h>

// ProbAttention on MI355X (gfx950). Inputs/outputs fp32; compute in bf16 MFMA
// (mfma_f32_16x16x32_bf16, fp32 accumulate). B=8, L=4096, D=512, H=8, DK=64,
// S=512, CONV_K=3, POOL=2.
//
// Pipeline:
//  0. cvt: x (fp32) -> xb (bf16)                 [B*L*512]
//  1. weight transposes fp32 -> bf16 Bt[N][K]    (Wq/Wk/Wv/comb 512x512, conv 1536x512)
//  2. gather xb rows: xkg (K path, double-gather collapsed), xvg (V path)
//  3. Kg = xkg @ Wk, Vg = xvg @ Wv  (bf16 GEMM)
//  4. Vt[b][e][s] = Vg[b][s][e]
//  5. fused attn (Q proj fused, flash-chunked over S) -> Pad[b][l+1][e]
//  6. conv-as-GEMM K=1536 + bias + ELU + MaxPool2 -> Pool [B][2048][512] bf16
//  7. final GEMM + bias -> out (fp32)
//
// Workspace (79.2 MB): xb@0 (Pool aliases after attn), Pad@32M (xkg/xvg/Vg alias
// head), Kg, Vt, then transposed weights.

typedef __attribute__((ext_vector_type(8))) short  short8;
typedef __attribute__((ext_vector_type(4))) float  f32x4;

#define LSEQ   4096
#define SK     512
#define EDIM   512
#define LPAD   4098            // L + 2
#define PADROW 2098176         // LPAD * 512 (shorts)

static __device__ __forceinline__ float bf2f(unsigned short h) {
    union { unsigned int u; float f; } v; v.u = ((unsigned int)h) << 16; return v.f;
}
static __device__ __forceinline__ unsigned short f2bf(float f) {
    union { float f; unsigned int u; } v; v.f = f;
    unsigned int r = (v.u + 0x7fffu + ((v.u >> 16) & 1u)) >> 16;
    return (unsigned short)r;
}

// ---------------------------------------------------------------- fp32 -> bf16
__global__ __launch_bounds__(256)
void cvt_bf16(const float* __restrict__ src, unsigned short* __restrict__ dst)
{
    const size_t i = ((size_t)blockIdx.x * 256 + threadIdx.x) * 8;
    const float4 a = *(const float4*)(src + i);
    const float4 b = *(const float4*)(src + i + 4);
    short8 o;
    o[0] = (short)f2bf(a.x); o[1] = (short)f2bf(a.y);
    o[2] = (short)f2bf(a.z); o[3] = (short)f2bf(a.w);
    o[4] = (short)f2bf(b.x); o[5] = (short)f2bf(b.y);
    o[6] = (short)f2bf(b.z); o[7] = (short)f2bf(b.w);
    *(short8*)(dst + i) = o;
}

// ---------------------------------------------------------------- transpose fp32 -> bf16
__global__ __launch_bounds__(256)
void tr_f32_bf16(unsigned short* __restrict__ dst, const float* __restrict__ src,
                 int R, int C)
{
    __shared__ unsigned short T[64][72];
    const int t  = threadIdx.x;
    const int r0 = blockIdx.y * 64, c0 = blockIdx.x * 64;
    const int row = t >> 2, cg = (t & 3) * 16;
    const float* s = src + (size_t)(r0 + row) * C + c0 + cg;
    const float4 f0 = *(const float4*)s;
    const float4 f1 = *(const float4*)(s + 4);
    const float4 f2 = *(const float4*)(s + 8);
    const float4 f3 = *(const float4*)(s + 12);
    T[row][cg + 0]  = f2bf(f0.x); T[row][cg + 1]  = f2bf(f0.y);
    T[row][cg + 2]  = f2bf(f0.z); T[row][cg + 3]  = f2bf(f0.w);
    T[row][cg + 4]  = f2bf(f1.x); T[row][cg + 5]  = f2bf(f1.y);
    T[row][cg + 6]  = f2bf(f1.z); T[row][cg + 7]  = f2bf(f1.w);
    T[row][cg + 8]  = f2bf(f2.x); T[row][cg + 9]  = f2bf(f2.y);
    T[row][cg + 10] = f2bf(f2.z); T[row][cg + 11] = f2bf(f2.w);
    T[row][cg + 12] = f2bf(f3.x); T[row][cg + 13] = f2bf(f3.y);
    T[row][cg + 14] = f2bf(f3.z); T[row][cg + 15] = f2bf(f3.w);
    __syncthreads();
    unsigned short* d = dst + (size_t)(c0 + row) * R + r0 + cg;
    short8 o0, o1;
    #pragma unroll
    for (int k = 0; k < 8; ++k) o0[k] = (short)T[cg + k][row];
    #pragma unroll
    for (int k = 0; k < 8; ++k) o1[k] = (short)T[cg + 8 + k][row];
    *(short8*)d       = o0;
    *(short8*)(d + 8) = o1;
}

// ---------------------------------------------------------------- transpose bf16
__global__ __launch_bounds__(256)
void tr_bf16(unsigned short* __restrict__ dst, const unsigned short* __restrict__ src,
             int R, int C)
{
    __shared__ unsigned short T[64][72];
    const size_t bofs = (size_t)blockIdx.z * (size_t)R * (size_t)C;
    src += bofs; dst += bofs;
    const int t  = threadIdx.x;
    const int r0 = blockIdx.y * 64, c0 = blockIdx.x * 64;
    const int row = t >> 2, cg = (t & 3) * 16;
    const unsigned short* s = src + (size_t)(r0 + row) * C + c0 + cg;
    *(short8*)&T[row][cg]     = *(const short8*)s;
    *(short8*)&T[row][cg + 8] = *(const short8*)(s + 8);
    __syncthreads();
    unsigned short* d = dst + (size_t)(c0 + row) * R + r0 + cg;
    short8 o0, o1;
    #pragma unroll
    for (int k = 0; k < 8; ++k) o0[k] = (short)T[cg + k][row];
    #pragma unroll
    for (int k = 0; k < 8; ++k) o1[k] = (short)T[cg + 8 + k][row];
    *(short8*)d       = o0;
    *(short8*)(d + 8) = o1;
}

// ---------------------------------------------------------------- gather rows (bf16)
__global__ __launch_bounds__(256)
void gather_rows(const unsigned short* __restrict__ xb, const int* __restrict__ sidx,
                 unsigned short* __restrict__ xkg, unsigned short* __restrict__ xvg)
{
    const int blk = blockIdx.x;
    const int b = blk >> 9, j = blk & 511;
    const int t = threadIdx.x;
    int qv = sidx[j];               qv = qv < 0 ? 0 : (qv > LSEQ - 1 ? LSEQ - 1 : qv);
    int cv = qv < SK - 1 ? qv : SK - 1;
    int pv = sidx[cv];              pv = pv < 0 ? 0 : (pv > LSEQ - 1 ? LSEQ - 1 : pv);
    const unsigned int* xs = (const unsigned int*)xb;
    unsigned int* kd = (unsigned int*)xkg;
    unsigned int* vd = (unsigned int*)xvg;
    const size_t dst = ((size_t)b * SK + j) * 256 + t;
    kd[dst] = xs[((size_t)b * LSEQ + pv) * 256 + t];
    vd[dst] = xs[((size_t)b * LSEQ + qv) * 256 + t];
}

// ---------------------------------------------------------------- zero pad rows
__global__ __launch_bounds__(256)
void zero_pad(unsigned short* __restrict__ attpad)
{
    const int i = blockIdx.x * 256 + threadIdx.x;   // 0..4095
    const int b = i >> 9, c = i & 511;
    attpad[(size_t)b * PADROW + c] = 0;
    attpad[(size_t)b * PADROW + (size_t)(LPAD - 1) * 512 + c] = 0;
}

// ---------------------------------------------------------------- GEMM 128x128x32
// MODE 0: bf16 store. MODE 1: conv epilogue (+bias, ELU, MaxPool2 -> bf16).
// MODE 2: +bias, fp32 store.
template<int MODE>
__global__ __launch_bounds__(256)
void gemm128(const unsigned short* __restrict__ A, const unsigned short* __restrict__ Bt,
             const float* __restrict__ bias, void* __restrict__ Cout, int K)
{
    __shared__ unsigned short As[128 * 40];
    __shared__ unsigned short Bs[128 * 40];
    const int t    = threadIdx.x;
    const int n0   = blockIdx.x * 128;
    const int m0   = blockIdx.y * 128;
    const int srow = t >> 1, scg = (t & 1) * 16;
    const int lane = t & 63, wv = t >> 6;
    const int q = lane >> 4, ln = lane & 15;
    const int wm = (wv & 1) * 64, wn = (wv >> 1) * 64;

    const unsigned short* abase;
    if (MODE == 1) {
        const int gr = m0 + srow;
        abase = A + (size_t)(gr >> 12) * PADROW + (size_t)(gr & 4095) * 512;
    } else {
        abase = A + (size_t)(m0 + srow) * K;
    }
    const unsigned short* bbase = Bt + (size_t)(n0 + srow) * K;

    const f32x4 zero = {0.f, 0.f, 0.f, 0.f};
    f32x4 acc[4][4];
    #pragma unroll
    for (int i = 0; i < 4; ++i)
        #pragma unroll
        for (int j = 0; j < 4; ++j) acc[i][j] = zero;

    short8 av0 = *(const short8*)(abase + scg);
    short8 av1 = *(const short8*)(abase + scg + 8);
    short8 bv0 = *(const short8*)(bbase + scg);
    short8 bv1 = *(const short8*)(bbase + scg + 8);

    for (int k0 = 0; k0 < K; k0 += 32) {
        __syncthreads();
        *(short8*)&As[srow * 40 + scg]     = av0;
        *(short8*)&As[srow * 40 + scg + 8] = av1;
        *(short8*)&Bs[srow * 40 + scg]     = bv0;
        *(short8*)&Bs[srow * 40 + scg + 8] = bv1;
        __syncthreads();
        if (k0 + 32 < K) {
            av0 = *(const short8*)(abase + k0 + 32 + scg);
            av1 = *(const short8*)(abase + k0 + 32 + scg + 8);
            bv0 = *(const short8*)(bbase + k0 + 32 + scg);
            bv1 = *(const short8*)(bbase + k0 + 32 + scg + 8);
        }
        short8 af[4], bf[4];
        #pragma unroll
        for (int mt = 0; mt < 4; ++mt)
            af[mt] = *(const short8*)&As[(wm + mt * 16 + ln) * 40 + q * 8];
        #pragma unroll
        for (int nt = 0; nt < 4; ++nt)
            bf[nt] = *(const short8*)&Bs[(wn + nt * 16 + ln) * 40 + q * 8];
        #pragma unroll
        for (int mt = 0; mt < 4; ++mt)
            #pragma unroll
            for (int nt = 0; nt < 4; ++nt)
                acc[mt][nt] = __builtin_amdgcn_mfma_f32_16x16x32_bf16(af[mt], bf[nt], acc[mt][nt], 0, 0, 0);
    }

    if (MODE == 0) {
        unsigned short* C = (unsigned short*)Cout;
        #pragma unroll
        for (int mt = 0; mt < 4; ++mt)
            #pragma unroll
            for (int r = 0; r < 4; ++r) {
                const int grow = m0 + wm + mt * 16 + q * 4 + r;
                unsigned short* cp = C + (size_t)grow * 512 + n0 + wn + ln;
                #pragma unroll
                for (int nt = 0; nt < 4; ++nt) cp[nt * 16] = f2bf(acc[mt][nt][r]);
            }
    } else if (MODE == 2) {
        float* C = (float*)Cout;
        float bb[4];
        #pragma unroll
        for (int nt = 0; nt < 4; ++nt) bb[nt] = bias[n0 + wn + nt * 16 + ln];
        #pragma unroll
        for (int mt = 0; mt < 4; ++mt)
            #pragma unroll
            for (int r = 0; r < 4; ++r) {
                const int grow = m0 + wm + mt * 16 + q * 4 + r;
                float* cp = C + (size_t)grow * 512 + n0 + wn + ln;
                #pragma unroll
                for (int nt = 0; nt < 4; ++nt) cp[nt * 16] = acc[mt][nt][r] + bb[nt];
            }
    } else { // MODE 1
        unsigned short* C = (unsigned short*)Cout;
        float bb[4];
        #pragma unroll
        for (int nt = 0; nt < 4; ++nt) bb[nt] = bias[n0 + wn + nt * 16 + ln];
        #pragma unroll
        for (int mt = 0; mt < 4; ++mt) {
            const int grow = m0 + wm + mt * 16 + q * 4;
            const int b = grow >> 12, l = grow & 4095;
            unsigned short* cp = C + ((size_t)b * 2048 + (l >> 1)) * 512 + n0 + wn + ln;
            #pragma unroll
            for (int nt = 0; nt < 4; ++nt) {
                float v0 = acc[mt][nt][0] + bb[nt]; v0 = v0 > 0.f ? v0 : __expf(v0) - 1.f;
                float v1 = acc[mt][nt][1] + bb[nt]; v1 = v1 > 0.f ? v1 : __expf(v1) - 1.f;
                float v2 = acc[mt][nt][2] + bb[nt]; v2 = v2 > 0.f ? v2 : __expf(v2) - 1.f;
                float v3 = acc[mt][nt][3] + bb[nt]; v3 = v3 > 0.f ? v3 : __expf(v3) - 1.f;
                cp[nt * 16]       = f2bf(fmaxf(v0, v1));
                cp[512 + nt * 16] = f2bf(fmaxf(v2, v3));
            }
        }
    }
}

// ---------------------------------------------------------------- fused attention v2
// Flash-chunked: grid (L/64, H, B), 256 threads = 4 waves; wave w owns q-rows
// w*16..w*16+15. S processed in 4 chunks of 128 with online softmax.
// K chunk staged cooperatively in LDS; next chunk prefetched to regs during PV.
// LDS: Ks 18,432 B + union(Ps 17,408 / Qs 9,216) = 35,840 B -> 4 blocks/CU.
__global__ __launch_bounds__(256, 4)
void attn_fused(const unsigned short* __restrict__ xb, const unsigned short* __restrict__ WqT,
                const unsigned short* __restrict__ Kg, const unsigned short* __restrict__ Vt,
                unsigned short* __restrict__ attpad)
{
    __shared__ unsigned short Ks[128][72];
    __shared__ union { unsigned short P[64][136]; unsigned short Q[64][72]; } U;
    const int t = threadIdx.x;
    const int wv = t >> 6, lane = t & 63, q = lane >> 4, ln = lane & 15;
    const int l0 = blockIdx.x * 64, h = blockIdx.y, b = blockIdx.z;
    const f32x4 zero = {0.f, 0.f, 0.f, 0.f};

    // --- phase 0: Q projection (m=16 rows of this wave, n=64 head cols, k=512)
    f32x4 qacc[4];
    #pragma unroll
    for (int i = 0; i < 4; ++i) qacc[i] = zero;
    const unsigned short* xr = xb + ((size_t)(b * LSEQ + l0 + wv * 16 + ln)) * 512 + q * 8;
    const unsigned short* wq = WqT + ((size_t)(h * 64 + ln)) * 512 + q * 8;
    for (int ks = 0; ks < 16; ++ks) {
        const short8 ax = *(const short8*)(xr + ks * 32);
        #pragma unroll
        for (int nt = 0; nt < 4; ++nt) {
            const short8 bw = *(const short8*)(wq + nt * 16 * 512 + ks * 32);
            qacc[nt] = __builtin_amdgcn_mfma_f32_16x16x32_bf16(ax, bw, qacc[nt], 0, 0, 0);
        }
    }
    #pragma unroll
    for (int nt = 0; nt < 4; ++nt)
        #pragma unroll
        for (int r = 0; r < 4; ++r)
            U.Q[wv * 16 + q * 4 + r][nt * 16 + ln] = f2bf(qacc[nt][r]);
    __syncthreads();
    const short8 aq0 = *(const short8*)&U.Q[wv * 16 + ln][q * 8];
    const short8 aq1 = *(const short8*)&U.Q[wv * 16 + ln][q * 8 + 32];
    __syncthreads();   // everyone has Q frags; U.Q dead, U.P reusable

    // --- flash state
    float m_run[4], l_run[4];
    f32x4 o[4];
    #pragma unroll
    for (int r = 0; r < 4; ++r) { m_run[r] = -1e30f; l_run[r] = 0.f; }
    #pragma unroll
    for (int j = 0; j < 4; ++j) o[j] = zero;

    // K staging map: thread t -> rows (t>>2, t>>2+64), short-offsets (t&3)*8, +32
    const int krow = t >> 2, kcol = (t & 3) * 8;
    const unsigned short* kbase = Kg + (size_t)b * SK * 512 + h * 64;
    // prefetch chunk 0
    short8 kv0 = *(const short8*)(kbase + (size_t)krow * 512 + kcol);
    short8 kv1 = *(const short8*)(kbase + (size_t)krow * 512 + kcol + 32);
    short8 kv2 = *(const short8*)(kbase + (size_t)(krow + 64) * 512 + kcol);
    short8 kv3 = *(const short8*)(kbase + (size_t)(krow + 64) * 512 + kcol + 32);

    const unsigned short* vbase = Vt + ((size_t)(b * EDIM + h * 64 + ln)) * SK + q * 8;

    for (int c = 0; c < 4; ++c) {
        // store staged K chunk (safe: all waves past prev chunk's barrier B)
        *(short8*)&Ks[krow][kcol]           = kv0;
        *(short8*)&Ks[krow][kcol + 32]      = kv1;
        *(short8*)&Ks[krow + 64][kcol]      = kv2;
        *(short8*)&Ks[krow + 64][kcol + 32] = kv3;
        __syncthreads();   // A: Ks ready (also: prev PV's U.P reads done)

        // scores for 16 rows x 128 cols of this chunk
        f32x4 sa[8];
        #pragma unroll
        for (int nt = 0; nt < 8; ++nt) {
            const short8 bk0 = *(const short8*)&Ks[nt * 16 + ln][q * 8];
            const short8 bk1 = *(const short8*)&Ks[nt * 16 + ln][q * 8 + 32];
            f32x4 a = zero;
            a = __builtin_amdgcn_mfma_f32_16x16x32_bf16(aq0, bk0, a, 0, 0, 0);
            a = __builtin_amdgcn_mfma_f32_16x16x32_bf16(aq1, bk1, a, 0, 0, 0);
            #pragma unroll
            for (int r = 0; r < 4; ++r) a[r] *= 0.125f;
            sa[nt] = a;
        }

        // online softmax update (rows q*4+r live on 16 lanes sharing quad q)
        float mx[4];
        #pragma unroll
        for (int r = 0; r < 4; ++r) {
            float m = sa[0][r];
            #pragma unroll
            for (int nt = 1; nt < 8; ++nt) m = fmaxf(m, sa[nt][r]);
            m = fmaxf(m, __shfl_xor(m, 1));
            m = fmaxf(m, __shfl_xor(m, 2));
            m = fmaxf(m, __shfl_xor(m, 4));
            m = fmaxf(m, __shfl_xor(m, 8));
            mx[r] = m;
        }
        #pragma unroll
        for (int r = 0; r < 4; ++r) {
            const float m_new = fmaxf(m_run[r], mx[r]);
            const float alpha = __expf(m_run[r] - m_new);
            m_run[r] = m_new;
            l_run[r] *= alpha;
            #pragma unroll
            for (int j = 0; j < 4; ++j) o[j][r] *= alpha;
            float ls = 0.f;
            #pragma unroll
            for (int nt = 0; nt < 8; ++nt) {
                const float p = __expf(sa[nt][r] - m_new);
                ls += p;
                U.P[wv * 16 + q * 4 + r][nt * 16 + ln] = f2bf(p);
            }
            ls += __shfl_xor(ls, 1);
            ls += __shfl_xor(ls, 2);
            ls += __shfl_xor(ls, 4);
            ls += __shfl_xor(ls, 8);
            l_run[r] += ls;
        }

        // prefetch next K chunk into regs (overlaps barrier + PV)
        if (c < 3) {
            const unsigned short* kn = kbase + (size_t)(c + 1) * 128 * 512;
            kv0 = *(const short8*)(kn + (size_t)krow * 512 + kcol);
            kv1 = *(const short8*)(kn + (size_t)krow * 512 + kcol + 32);
            kv2 = *(const short8*)(kn + (size_t)(krow + 64) * 512 + kcol);
            kv3 = *(const short8*)(kn + (size_t)(krow + 64) * 512 + kcol + 32);
        }
        __syncthreads();   // B: U.P ready, Ks reads done

        // PV: m = 16 q-rows, n = 64 d, k = 128 chunk
        #pragma unroll
        for (int ks2 = 0; ks2 < 4; ++ks2) {
            const short8 ap = *(const short8*)&U.P[wv * 16 + ln][ks2 * 32 + q * 8];
            #pragma unroll
            for (int j = 0; j < 4; ++j) {
                const short8 bv = *(const short8*)(vbase + (size_t)(j * 16) * SK + c * 128 + ks2 * 32);
                o[j] = __builtin_amdgcn_mfma_f32_16x16x32_bf16(ap, bv, o[j], 0, 0, 0);
            }
        }
    }

    // epilogue: scale by 1/l, store to att_pad rows l0+1..l0+64
    float inv[4];
    #pragma unroll
    for (int r = 0; r < 4; ++r) inv[r] = 1.f / l_run[r];
    #pragma unroll
    for (int j = 0; j < 4; ++j)
        #pragma unroll
        for (int r = 0; r < 4; ++r) {
            const int rl = wv * 16 + q * 4 + r;
            attpad[((size_t)b * PADROW) + (size_t)(l0 + rl + 1) * 512 + h * 64 + j * 16 + ln]
                = f2bf(o[j][r] * inv[r]);
        }
}

// ---------------------------------------------------------------- launcher
extern "C" void kernel_launch(void* const* d_in, const int* in_sizes, int n_in,
                              void* d_out, int out_size, void* d_ws, size_t ws_size,
                              hipStream_t stream)
{
    const float* x    = (const float*)d_in[0];
    const float* Wq   = (const float*)d_in[1];
    const float* Wk   = (const float*)d_in[2];
    const float* Wv   = (const float*)d_in[3];
    const float* cw   = (const float*)d_in[4];   // [1536][512] flat fp32
    const float* cb   = (const float*)d_in[5];
    const float* mb2  = (const float*)d_in[7];
    const float* mw   = (const float*)d_in[6];
    const int*   sidx = (const int*)d_in[8];
    float* out = (float*)d_out;

    char* ws = (char*)d_ws;
    unsigned short* xb    = (unsigned short*)(ws + 0);           // 33,554,432 B
    unsigned short* Pool  = (unsigned short*)(ws + 0);           // alias (xb dead post-attn)
    unsigned short* Pad   = (unsigned short*)(ws + 33554432);    // 33,570,816 B
    unsigned short* xkg   = (unsigned short*)(ws + 33554432);    // alias Pad head
    unsigned short* xvg   = (unsigned short*)(ws + 37748736);    // alias
    unsigned short* Vg    = (unsigned short*)(ws + 41943040);    // alias
    unsigned short* Kg    = (unsigned short*)(ws + 67125248);    //  4,194,304 B
    unsigned short* Vt    = (unsigned short*)(ws + 71319552);    //  4,194,304 B
    unsigned short* WqT   = (unsigned short*)(ws + 75513856);    //    524,288 B
    unsigned short* WkT   = (unsigned short*)(ws + 76038144);
    unsigned short* WvT   = (unsigned short*)(ws + 76562432);
    unsigned short* CombT = (unsigned short*)(ws + 77086720);
    unsigned short* ConvT = (unsigned short*)(ws + 77611008);    // 1,572,864 B -> end 79,183,872

    dim3 blk(256);

    // 0. x -> bf16
    cvt_bf16<<<dim3(8192), blk, 0, stream>>>(x, xb);

    // 1. weight transposes (fp32 -> bf16): dst[N][K] = W[K][N]
    tr_f32_bf16<<<dim3(8, 8),  blk, 0, stream>>>(WqT,   Wq, 512, 512);
    tr_f32_bf16<<<dim3(8, 8),  blk, 0, stream>>>(WkT,   Wk, 512, 512);
    tr_f32_bf16<<<dim3(8, 8),  blk, 0, stream>>>(WvT,   Wv, 512, 512);
    tr_f32_bf16<<<dim3(8, 8),  blk, 0, stream>>>(CombT, mw, 512, 512);
    tr_f32_bf16<<<dim3(8, 24), blk, 0, stream>>>(ConvT, cw, 1536, 512);

    // 2. gathers (xkg/xvg in Pad head; consumed before zero_pad/attn)
    gather_rows<<<dim3(4096), blk, 0, stream>>>(xb, sidx, xkg, xvg);

    // 3. K/V projections (per-batch 512 gathered rows)
    gemm128<0><<<dim3(4, 32), blk, 0, stream>>>(xkg, WkT, nullptr, Kg, 512);
    gemm128<0><<<dim3(4, 32), blk, 0, stream>>>(xvg, WvT, nullptr, Vg, 512);

    // 4. Vt[b][e][s] = Vg[b][s][e]
    tr_bf16<<<dim3(8, 8, 8), blk, 0, stream>>>(Vt, Vg, 512, 512);

    // 5. attention (Q projection fused, flash-chunked; writes Pad rows 1..L)
    zero_pad<<<dim3(16), blk, 0, stream>>>(Pad);
    attn_fused<<<dim3(64, 8, 8), blk, 0, stream>>>(xb, WqT, Kg, Vt, Pad);

    // 6. conv (K=1536) + bias + ELU + pool -> Pool (aliases dead xb)
    gemm128<1><<<dim3(4, 256), blk, 0, stream>>>(Pad, ConvT, cb, Pool, 1536);

    // 7. final dense + bias -> out (fp32)
    gemm128<2><<<dim3(4, 128), blk, 0, stream>>>(Pool, CombT, mb2, out, 512);
}